// Round 20
// baseline (1085.254 us; speedup 1.0000x reference)
//
#include <hip/hip_runtime.h>
#include <math.h>

#define NB 256
#define NS 100
#define ND 512
#define NH 8
#define NDFF 2048
#define NL 4
#define NM (NB * NS)  // 25600 tokens

typedef unsigned short u16;
typedef unsigned short u16x4 __attribute__((ext_vector_type(4)));
typedef unsigned short u16x8 __attribute__((ext_vector_type(8)));
typedef __bf16 bf16x8 __attribute__((ext_vector_type(8)));
typedef float f32x4 __attribute__((ext_vector_type(4)));
typedef _Float16 f16x2 __attribute__((ext_vector_type(2)));
typedef _Float16 f16x8 __attribute__((ext_vector_type(8)));

#if __has_builtin(__builtin_amdgcn_fdot2)
#define USE_FDOT2 1
#else
#define USE_FDOT2 0
#endif

__device__ __forceinline__ float b2f(u16 u) {
  unsigned v = ((unsigned)u) << 16;
  return __builtin_bit_cast(float, v);
}
__device__ __forceinline__ u16 f2b(float f) {
  unsigned u = __builtin_bit_cast(unsigned, f);
  u += 0x7fffu + ((u >> 16) & 1u);
  return (u16)(u >> 16);
}
// async global->LDS, 16B per lane; LDS dest is wave-uniform base (HW adds lane*16)
__device__ __forceinline__ void gload_lds16(const void* g, void* l) {
  __builtin_amdgcn_global_load_lds(
      (const __attribute__((address_space(1))) unsigned int*)g,
      (__attribute__((address_space(3))) unsigned int*)l, 16, 0, 0);
}

// ---------------------------------------------------------------------------
// f32 -> bf16 cast (weights)
// ---------------------------------------------------------------------------
__global__ __launch_bounds__(256) void cast_kernel(const float* __restrict__ in,
                                                   u16* __restrict__ out) {
  int i = blockIdx.x * 256 + threadIdx.x;
  float4 v = ((const float4*)in)[i];
  u16x4 o = {f2b(v.x), f2b(v.y), f2b(v.z), f2b(v.w)};
  ((u16x4*)out)[i] = o;
}

// ---------------------------------------------------------------------------
// Per-batch lengths (prefix mask) + exclusive scan + per-chunk token counts
// + LPT schedule order (descending len, index tie-break). Results-invariant.
// ---------------------------------------------------------------------------
__global__ __launch_bounds__(256) void scan_kernel(const int* __restrict__ mask,
                                                   int* __restrict__ offs,
                                                   int* __restrict__ meta,
                                                   int* __restrict__ order,
                                                   int BC, int NC) {
  const int b = threadIdx.x;
  const int* mp = mask + b * NS;
  int len = 0;
#pragma unroll
  for (int i = 0; i < NS; i += 4) {
    int4 v = *(const int4*)(mp + i);
    len += v.x + v.y + v.z + v.w;
  }
  int v = len;
#pragma unroll
  for (int off = 1; off < 64; off <<= 1) {
    int u = __shfl_up(v, off);
    if ((b & 63) >= off) v += u;
  }
  __shared__ int wsum[4];
  __shared__ int incl[256];
  __shared__ int slen[256];
  slen[b] = len;
  if ((b & 63) == 63) wsum[b >> 6] = v;
  __syncthreads();
  int add = 0;
  for (int w = 0; w < (b >> 6); ++w) add += wsum[w];
  v += add;
  incl[b] = v;
  offs[b + 1] = v;
  if (b == 0) offs[0] = 0;
  __syncthreads();
  if (b < NC) meta[b] = incl[(b + 1) * BC - 1] - (b ? incl[b * BC - 1] : 0);
  // LPT rank within this batch's chunk (descending len, unique via idx tie)
  const int c0 = (b / BC) * BC;
  int rank = 0;
  for (int j = c0; j < c0 + BC; ++j)
    rank += (slen[j] > len) || (slen[j] == len && j < b);
  order[c0 + rank] = b;
}

// ---------------------------------------------------------------------------
// Fused PE-add + COMPACTION gather: real token (b,s) -> compacted row of its
// chunk. One block per source token; padded tokens exit (prefix mask).
// ---------------------------------------------------------------------------
__global__ __launch_bounds__(128) void pe_compact_kernel(const float* __restrict__ emb,
                                                         const int* __restrict__ offs,
                                                         int BC,
                                                         float* __restrict__ x,
                                                         u16* __restrict__ xb) {
  const int tok = blockIdx.x;
  const int b = tok / NS, s = tok - b * NS;
  const int ob = offs[b];
  const int len = offs[b + 1] - ob;
  if (s >= len) return;
  const int c = b / BC;
  const size_t dst = ((size_t)c * BC * NS + (ob - offs[c * BC]) + s) * ND;
  const int t = threadIdx.x;
  const int d0 = t * 4;
  float4 ev = *(const float4*)(emb + (size_t)tok * ND + d0);
  float o[4];
#pragma unroll
  for (int e = 0; e < 4; ++e) {
    int d = d0 + e;
    float ang = (float)s * (float)(d & ~1) * (-4.6051701859880914f / (float)ND);
    float pe = (d & 1) ? __cosf(ang) : __sinf(ang);
    o[e] = ((const float*)&ev)[e] + pe;
  }
  *(float4*)(x + dst + d0) = (float4){o[0], o[1], o[2], o[3]};
  u16x4 ob16 = {f2b(o[0]), f2b(o[1]), f2b(o[2]), f2b(o[3])};
  *(u16x4*)(xb + dst + d0) = ob16;
}

// ---------------------------------------------------------------------------
// C = A @ W^T + bias (+R residual) (optional ReLU). A: MxK bf16, W: NxK bf16.
// TM x 128 tile (TM=128 or 64), BK=64, 4 waves. Linear LDS via global_load_lds
// w/ pre-swizzled source; ds_read applies blk ^= (row&7) -> conflict-free.
// Round-13/14 PROVEN epilogue. RESID may be IN-PLACE (R == Cf).
// VARLEN early-exit beyond round-up-TM(*pMr).
// C/D: col = lane&15, row = (lane>>4)*4 + j   [verified rounds 2-19]
// ---------------------------------------------------------------------------
template <int TM, bool RELU, bool OUTBF16, bool RESID>
__global__ __launch_bounds__(256) void gemm_mfma(const u16* __restrict__ A,
                                                 const u16* __restrict__ W,
                                                 const float* __restrict__ bias,
                                                 const float* __restrict__ R,
                                                 float* __restrict__ Cf,
                                                 u16* __restrict__ Cb,
                                                 const int* __restrict__ pMr,
                                                 int N, int K) {
  constexpr int MF = TM / 32;  // m-fragments per wave (wave rows = 16*MF)
  const int m0 = blockIdx.y * TM, n0 = blockIdx.x * 128;
  if (m0 >= ((*pMr + TM - 1) & ~(TM - 1))) return;  // uniform early-exit
  __shared__ u16 As[TM * 64];
  __shared__ u16 Ws[128 * 64];
  const int t = threadIdx.x;
  const int lane = t & 63;
  const int wave = t >> 6;
  const int wr = wave >> 1, wc = wave & 1;
  const int srow = lane >> 3;
  const int sblk = (lane & 7) ^ srow;
  const u16* gA = A + (size_t)(m0 + wave * 8 + srow) * K + sblk * 8;
  const u16* gW = W + (size_t)(n0 + wave * 8 + srow) * K + sblk * 8;
  u16* lA = As + wave * 512;
  u16* lW = Ws + wave * 512;
  f32x4 acc[MF][4];
#pragma unroll
  for (int m = 0; m < MF; ++m)
#pragma unroll
    for (int n = 0; n < 4; ++n) acc[m][n] = (f32x4){0.f, 0.f, 0.f, 0.f};
  const int lg = lane >> 4;
  const int li = lane & 15;
  const int l7 = li & 7;
  for (int k0 = 0; k0 < K; k0 += 64) {
    __syncthreads();
#pragma unroll
    for (int i = 0; i < MF; ++i)
      gload_lds16(gA + k0 + (size_t)(32 * i) * K, lA + i * 2048);
#pragma unroll
    for (int i = 0; i < 4; ++i)
      gload_lds16(gW + k0 + (size_t)(32 * i) * K, lW + i * 2048);
    __syncthreads();
#pragma unroll
    for (int h = 0; h < 2; ++h) {
      bf16x8 af[MF], bf_[4];
#pragma unroll
      for (int m = 0; m < MF; ++m) {
        int row = wr * (16 * MF) + m * 16 + li;
        af[m] = __builtin_bit_cast(
            bf16x8, *(const u16x8*)&As[row * 64 + (((h << 2) + lg) ^ l7) * 8]);
      }
#pragma unroll
      for (int n = 0; n < 4; ++n) {
        int row = wc * 64 + n * 16 + li;
        bf_[n] = __builtin_bit_cast(
            bf16x8, *(const u16x8*)&Ws[row * 64 + (((h << 2) + lg) ^ l7) * 8]);
      }
#pragma unroll
      for (int m = 0; m < MF; ++m)
#pragma unroll
        for (int n = 0; n < 4; ++n)
          acc[m][n] = __builtin_amdgcn_mfma_f32_16x16x32_bf16(af[m], bf_[n], acc[m][n], 0, 0, 0);
    }
  }
#pragma unroll
  for (int m = 0; m < MF; ++m) {
    int row = m0 + wr * (16 * MF) + m * 16 + lg * 4;
#pragma unroll
    for (int n = 0; n < 4; ++n) {
      int col = n0 + wc * 64 + n * 16 + li;
      float bv = bias[col];
#pragma unroll
      for (int j = 0; j < 4; ++j) {
        float v = acc[m][n][j] + bv;
        if (RESID) v += R[(size_t)(row + j) * N + col];
        if (RELU) v = fmaxf(v, 0.f);
        if (OUTBF16) Cb[(size_t)(row + j) * N + col] = f2b(v);
        else Cf[(size_t)(row + j) * N + col] = v;
      }
    }
  }
}

// ---------------------------------------------------------------------------
// Q-register load helpers (f16 pairs when fdot2 available).
// ---------------------------------------------------------------------------
#if USE_FDOT2
#define QREGS f16x2 qh[32]
#define LOADQ(gq)                                   \
  _Pragma("unroll") for (int j = 0; j < 8; ++j) {   \
    u16x8 qq = *(const u16x8*)((gq) + j * 8);       \
    _Pragma("unroll") for (int e = 0; e < 4; ++e) { \
      f16x2 p;                                      \
      p[0] = (_Float16)b2f(qq[e * 2 + 0]);          \
      p[1] = (_Float16)b2f(qq[e * 2 + 1]);          \
      qh[j * 4 + e] = p;                            \
    }                                               \
  }
#else
#define QREGS float qh[64]
#define LOADQ(gq)                                   \
  _Pragma("unroll") for (int j = 0; j < 8; ++j) {   \
    u16x8 qq = *(const u16x8*)((gq) + j * 8);       \
    _Pragma("unroll") for (int e = 0; e < 8; ++e)   \
      qh[j * 8 + e] = b2f(qq[e]) * 0.125f;          \
  }
#endif

// ---------------------------------------------------------------------------
// VARLEN attention, SINGLE-pass fallback (round-13 proven, 38.4 KB LDS).
// ---------------------------------------------------------------------------
__global__ __launch_bounds__(128) void attn_kernel(const u16* __restrict__ qkv,
                                                   const int* __restrict__ offs,
                                                   const int* __restrict__ order,
                                                   int bBase,
                                                   u16* __restrict__ out) {
  const int bh = blockIdx.x;
  const int bl = bh >> 3, h = bh & 7;
  const int bg = order[bBase + bl];       // LPT order (results-invariant)
  const int ob = offs[bg] - offs[bBase];
  const int len = offs[bg + 1] - offs[bg];  // >= 1
  __shared__ u16 Ksb[NS * 64];
  __shared__ float Vs[NS * 64];
  const int t = threadIdx.x;
  const u16* base = qkv + (size_t)ob * 1536 + h * 64;

  for (int e = t; e < len * 16; e += 128) {
    int s = e >> 4, d4 = (e & 15) << 2;
    u16x4 kk = *(const u16x4*)(base + (size_t)s * 1536 + 512 + d4);
#if USE_FDOT2
    u16x4 kh;
#pragma unroll
    for (int q = 0; q < 4; ++q) {
      _Float16 hv = (_Float16)b2f(kk[q]);
      kh[q] = __builtin_bit_cast(u16, hv);
    }
    *(u16x4*)&Ksb[s * 64 + d4] = kh;
#else
    *(u16x4*)&Ksb[s * 64 + d4] = kk;
#endif
    u16x4 vv = *(const u16x4*)(base + (size_t)s * 1536 + 1024 + d4);
    Vs[s * 64 + d4 + 0] = b2f(vv[0]);
    Vs[s * 64 + d4 + 1] = b2f(vv[1]);
    Vs[s * 64 + d4 + 2] = b2f(vv[2]);
    Vs[s * 64 + d4 + 3] = b2f(vv[3]);
  }
  QREGS;
  if (t < len) { LOADQ(base + (size_t)t * 1536); }
  __syncthreads();
  if (t >= len) return;

  f32x4 acc[16];
#pragma unroll
  for (int dq = 0; dq < 16; ++dq) acc[dq] = (f32x4){0.f, 0.f, 0.f, 0.f};
  float m = -INFINITY, sum = 0.f;
  int s = 0;
  for (; s + 2 <= len; s += 2) {
    float a0 = 0.f, a1 = 0.f, a2 = 0.f, a3 = 0.f;
    float c0 = 0.f, c1 = 0.f, c2 = 0.f, c3 = 0.f;
#if USE_FDOT2
#pragma unroll
    for (int j = 0; j < 8; ++j) {
      f16x8 ka = __builtin_bit_cast(f16x8, *(const u16x8*)&Ksb[s * 64 + j * 8]);
      f16x8 kb = __builtin_bit_cast(f16x8, *(const u16x8*)&Ksb[(s + 1) * 64 + j * 8]);
      f16x2 ka0 = {ka[0], ka[1]}, ka1 = {ka[2], ka[3]};
      f16x2 ka2 = {ka[4], ka[5]}, ka3 = {ka[6], ka[7]};
      f16x2 kb0 = {kb[0], kb[1]}, kb1 = {kb[2], kb[3]};
      f16x2 kb2 = {kb[4], kb[5]}, kb3 = {kb[6], kb[7]};
      a0 = __builtin_amdgcn_fdot2(qh[j * 4 + 0], ka0, a0, false);
      c0 = __builtin_amdgcn_fdot2(qh[j * 4 + 0], kb0, c0, false);
      a1 = __builtin_amdgcn_fdot2(qh[j * 4 + 1], ka1, a1, false);
      c1 = __builtin_amdgcn_fdot2(qh[j * 4 + 1], kb1, c1, false);
      a2 = __builtin_amdgcn_fdot2(qh[j * 4 + 2], ka2, a2, false);
      c2 = __builtin_amdgcn_fdot2(qh[j * 4 + 2], kb2, c2, false);
      a3 = __builtin_amdgcn_fdot2(qh[j * 4 + 3], ka3, a3, false);
      c3 = __builtin_amdgcn_fdot2(qh[j * 4 + 3], kb3, c3, false);
    }
    float a = ((a0 + a1) + (a2 + a3)) * 0.125f;
    float c = ((c0 + c1) + (c2 + c3)) * 0.125f;
#else
#pragma unroll
    for (int j = 0; j < 8; ++j) {
      u16x8 ka = *(const u16x8*)&Ksb[s * 64 + j * 8];
      u16x8 kb = *(const u16x8*)&Ksb[(s + 1) * 64 + j * 8];
      a0 += qh[j * 8 + 0] * b2f(ka[0]); c0 += qh[j * 8 + 0] * b2f(kb[0]);
      a1 += qh[j * 8 + 1] * b2f(ka[1]); c1 += qh[j * 8 + 1] * b2f(kb[1]);
      a2 += qh[j * 8 + 2] * b2f(ka[2]); c2 += qh[j * 8 + 2] * b2f(kb[2]);
      a3 += qh[j * 8 + 3] * b2f(ka[3]); c3 += qh[j * 8 + 3] * b2f(kb[3]);
      a0 += qh[j * 8 + 4] * b2f(ka[4]); c0 += qh[j * 8 + 4] * b2f(kb[4]);
      a1 += qh[j * 8 + 5] * b2f(ka[5]); c1 += qh[j * 8 + 5] * b2f(kb[5]);
      a2 += qh[j * 8 + 6] * b2f(ka[6]); c2 += qh[j * 8 + 6] * b2f(kb[6]);
      a3 += qh[j * 8 + 7] * b2f(ka[7]); c3 += qh[j * 8 + 7] * b2f(kb[7]);
    }
    float a = (a0 + a1) + (a2 + a3);
    float c = (c0 + c1) + (c2 + c3);
#endif
    float mx2 = fmaxf(a, c);
    if (mx2 > m + 8.f) {
      float cs = __expf(m - mx2);
      sum *= cs;
#pragma unroll
      for (int dq = 0; dq < 16; ++dq) acc[dq] *= cs;
      m = mx2;
    }
    float pa = __expf(a - m);
    float pc = __expf(c - m);
    sum += pa + pc;
#pragma unroll
    for (int dq = 0; dq < 16; ++dq) {
      f32x4 va = *(const f32x4*)&Vs[s * 64 + dq * 4];
      f32x4 vb = *(const f32x4*)&Vs[(s + 1) * 64 + dq * 4];
      acc[dq] += pa * va + pc * vb;
    }
  }
  if (s < len) {
    float a0 = 0.f, a1 = 0.f, a2 = 0.f, a3 = 0.f;
#if USE_FDOT2
#pragma unroll
    for (int j = 0; j < 8; ++j) {
      f16x8 ka = __builtin_bit_cast(f16x8, *(const u16x8*)&Ksb[s * 64 + j * 8]);
      f16x2 ka0 = {ka[0], ka[1]}, ka1 = {ka[2], ka[3]};
      f16x2 ka2 = {ka[4], ka[5]}, ka3 = {ka[6], ka[7]};
      a0 = __builtin_amdgcn_fdot2(qh[j * 4 + 0], ka0, a0, false);
      a1 = __builtin_amdgcn_fdot2(qh[j * 4 + 1], ka1, a1, false);
      a2 = __builtin_amdgcn_fdot2(qh[j * 4 + 2], ka2, a2, false);
      a3 = __builtin_amdgcn_fdot2(qh[j * 4 + 3], ka3, a3, false);
    }
    float a = ((a0 + a1) + (a2 + a3)) * 0.125f;
#else
#pragma unroll
    for (int j = 0; j < 8; ++j) {
      u16x8 ka = *(const u16x8*)&Ksb[s * 64 + j * 8];
      a0 += qh[j * 8 + 0] * b2f(ka[0]);
      a1 += qh[j * 8 + 1] * b2f(ka[1]);
      a2 += qh[j * 8 + 2] * b2f(ka[2]);
      a3 += qh[j * 8 + 3] * b2f(ka[3]);
      a0 += qh[j * 8 + 4] * b2f(ka[4]);
      a1 += qh[j * 8 + 5] * b2f(ka[5]);
      a2 += qh[j * 8 + 6] * b2f(ka[6]);
      a3 += qh[j * 8 + 7] * b2f(ka[7]);
    }
    float a = (a0 + a1) + (a2 + a3);
#endif
    if (a > m + 8.f) {
      float cs = __expf(m - a);
      sum *= cs;
#pragma unroll
      for (int dq = 0; dq < 16; ++dq) acc[dq] *= cs;
      m = a;
    }
    float p = __expf(a - m);
    sum += p;
#pragma unroll
    for (int dq = 0; dq < 16; ++dq)
      acc[dq] += p * *(const f32x4*)&Vs[s * 64 + dq * 4];
  }
  float inv = 1.f / sum;
  u16* op = out + (size_t)(ob + t) * ND + h * 64;
#pragma unroll
  for (int j = 0; j < 8; ++j) {
    u16x8 o;
#pragma unroll
    for (int e = 0; e < 8; ++e) {
      int d = j * 8 + e;
      o[e] = f2b(acc[d >> 2][d & 3] * inv);
    }
    *(u16x8*)(op + j * 8) = o;
  }
}

// ---------------------------------------------------------------------------
// VARLEN attention, KEY-SPLIT. ROUND-20: 1-D grid with SIDE INTERLEAVED into
// the low bit: item = blockIdx.x; side = item & 1; bh = item >> 1.
// Round-19's (x=bh, y=side) grid dispatched ALL side-0 blocks before any
// side-1 block, so side-1's longest batches (half the long-pole work)
// started ~4096 blocks late — recreating the tail LPT was meant to remove.
// Now both sides of the longest batches launch first. Results-invariant.
// LDS 19.3 KB; f32 V (r17 A/B). Partials: acc bf16 -> part[side], (m,sum).
// ---------------------------------------------------------------------------
#define KHALF 50
__global__ __launch_bounds__(128) void attn_split_kernel(const u16* __restrict__ qkv,
                                                         const int* __restrict__ offs,
                                                         const int* __restrict__ order,
                                                         int bBase, int Mc,
                                                         u16* __restrict__ part0,
                                                         u16* __restrict__ part1,
                                                         float2* __restrict__ msum) {
  const int item = blockIdx.x;
  const int side = item & 1;
  const int bh = item >> 1;
  const int bl = bh >> 3, h = bh & 7;
  const int bg = order[bBase + bl];       // LPT order (results-invariant)
  const int ob = offs[bg] - offs[bBase];
  const int len = offs[bg + 1] - offs[bg];  // >= 1
  const int hl = (len + 1) >> 1;
  const int k0 = side ? hl : 0;
  const int k1 = side ? len : hl;
  const int nk = k1 - k0;  // side 0: >=1, side 1: may be 0
  __shared__ u16 Ksb[KHALF * 64];   // 6.4 KB
  __shared__ float Vs[KHALF * 64];  // 12.8 KB
  const int t = threadIdx.x;
  const u16* baseQ = qkv + (size_t)ob * 1536 + h * 64;
  const u16* baseK = baseQ + (size_t)k0 * 1536;

  for (int e = t; e < nk * 16; e += 128) {
    int s = e >> 4, d4 = (e & 15) << 2;
    u16x4 kk = *(const u16x4*)(baseK + (size_t)s * 1536 + 512 + d4);
#if USE_FDOT2
    u16x4 kh;
#pragma unroll
    for (int q = 0; q < 4; ++q) {
      _Float16 hv = (_Float16)b2f(kk[q]);
      kh[q] = __builtin_bit_cast(u16, hv);
    }
    *(u16x4*)&Ksb[s * 64 + d4] = kh;
#else
    *(u16x4*)&Ksb[s * 64 + d4] = kk;
#endif
    u16x4 vv = *(const u16x4*)(baseK + (size_t)s * 1536 + 1024 + d4);
    Vs[s * 64 + d4 + 0] = b2f(vv[0]);
    Vs[s * 64 + d4 + 1] = b2f(vv[1]);
    Vs[s * 64 + d4 + 2] = b2f(vv[2]);
    Vs[s * 64 + d4 + 3] = b2f(vv[3]);
  }
  QREGS;
  if (t < len) { LOADQ(baseQ + (size_t)t * 1536); }
  __syncthreads();
  if (t >= len) return;

  f32x4 acc[16];
#pragma unroll
  for (int dq = 0; dq < 16; ++dq) acc[dq] = (f32x4){0.f, 0.f, 0.f, 0.f};
  float m = -INFINITY, sum = 0.f;
  int s = 0;
  for (; s + 2 <= nk; s += 2) {
    float a0 = 0.f, a1 = 0.f, a2 = 0.f, a3 = 0.f;
    float c0 = 0.f, c1 = 0.f, c2 = 0.f, c3 = 0.f;
#if USE_FDOT2
#pragma unroll
    for (int j = 0; j < 8; ++j) {
      f16x8 ka = __builtin_bit_cast(f16x8, *(const u16x8*)&Ksb[s * 64 + j * 8]);
      f16x8 kb = __builtin_bit_cast(f16x8, *(const u16x8*)&Ksb[(s + 1) * 64 + j * 8]);
      f16x2 ka0 = {ka[0], ka[1]}, ka1 = {ka[2], ka[3]};
      f16x2 ka2 = {ka[4], ka[5]}, ka3 = {ka[6], ka[7]};
      f16x2 kb0 = {kb[0], kb[1]}, kb1 = {kb[2], kb[3]};
      f16x2 kb2 = {kb[4], kb[5]}, kb3 = {kb[6], kb[7]};
      a0 = __builtin_amdgcn_fdot2(qh[j * 4 + 0], ka0, a0, false);
      c0 = __builtin_amdgcn_fdot2(qh[j * 4 + 0], kb0, c0, false);
      a1 = __builtin_amdgcn_fdot2(qh[j * 4 + 1], ka1, a1, false);
      c1 = __builtin_amdgcn_fdot2(qh[j * 4 + 1], kb1, c1, false);
      a2 = __builtin_amdgcn_fdot2(qh[j * 4 + 2], ka2, a2, false);
      c2 = __builtin_amdgcn_fdot2(qh[j * 4 + 2], kb2, c2, false);
      a3 = __builtin_amdgcn_fdot2(qh[j * 4 + 3], ka3, a3, false);
      c3 = __builtin_amdgcn_fdot2(qh[j * 4 + 3], kb3, c3, false);
    }
    float a = ((a0 + a1) + (a2 + a3)) * 0.125f;
    float c = ((c0 + c1) + (c2 + c3)) * 0.125f;
#else
#pragma unroll
    for (int j = 0; j < 8; ++j) {
      u16x8 ka = *(const u16x8*)&Ksb[s * 64 + j * 8];
      u16x8 kb = *(const u16x8*)&Ksb[(s + 1) * 64 + j * 8];
      a0 += qh[j * 8 + 0] * b2f(ka[0]); c0 += qh[j * 8 + 0] * b2f(kb[0]);
      a1 += qh[j * 8 + 1] * b2f(ka[1]); c1 += qh[j * 8 + 1] * b2f(kb[1]);
      a2 += qh[j * 8 + 2] * b2f(ka[2]); c2 += qh[j * 8 + 2] * b2f(kb[2]);
      a3 += qh[j * 8 + 3] * b2f(ka[3]); c3 += qh[j * 8 + 3] * b2f(kb[3]);
      a0 += qh[j * 8 + 4] * b2f(ka[4]); c0 += qh[j * 8 + 4] * b2f(kb[4]);
      a1 += qh[j * 8 + 5] * b2f(ka[5]); c1 += qh[j * 8 + 5] * b2f(kb[5]);
      a2 += qh[j * 8 + 6] * b2f(ka[6]); c2 += qh[j * 8 + 6] * b2f(kb[6]);
      a3 += qh[j * 8 + 7] * b2f(ka[7]); c3 += qh[j * 8 + 7] * b2f(kb[7]);
    }
    float a = (a0 + a1) + (a2 + a3);
    float c = (c0 + c1) + (c2 + c3);
#endif
    float mx2 = fmaxf(a, c);
    if (mx2 > m + 8.f) {
      float cs = __expf(m - mx2);
      sum *= cs;
#pragma unroll
      for (int dq = 0; dq < 16; ++dq) acc[dq] *= cs;
      m = mx2;
    }
    float pa = __expf(a - m);
    float pc = __expf(c - m);
    sum += pa + pc;
#pragma unroll
    for (int dq = 0; dq < 16; ++dq) {
      f32x4 va = *(const f32x4*)&Vs[s * 64 + dq * 4];
      f32x4 vb = *(const f32x4*)&Vs[(s + 1) * 64 + dq * 4];
      acc[dq] += pa * va + pc * vb;
    }
  }
  if (s < nk) {
    float a0 = 0.f, a1 = 0.f, a2 = 0.f, a3 = 0.f;
#if USE_FDOT2
#pragma unroll
    for (int j = 0; j < 8; ++j) {
      f16x8 ka = __builtin_bit_cast(f16x8, *(const u16x8*)&Ksb[s * 64 + j * 8]);
      f16x2 ka0 = {ka[0], ka[1]}, ka1 = {ka[2], ka[3]};
      f16x2 ka2 = {ka[4], ka[5]}, ka3 = {ka[6], ka[7]};
      a0 = __builtin_amdgcn_fdot2(qh[j * 4 + 0], ka0, a0, false);
      a1 = __builtin_amdgcn_fdot2(qh[j * 4 + 1], ka1, a1, false);
      a2 = __builtin_amdgcn_fdot2(qh[j * 4 + 2], ka2, a2, false);
      a3 = __builtin_amdgcn_fdot2(qh[j * 4 + 3], ka3, a3, false);
    }
    float a = ((a0 + a1) + (a2 + a3)) * 0.125f;
#else
#pragma unroll
    for (int j = 0; j < 8; ++j) {
      u16x8 ka = *(const u16x8*)&Ksb[s * 64 + j * 8];
      a0 += qh[j * 8 + 0] * b2f(ka[0]);
      a1 += qh[j * 8 + 1] * b2f(ka[1]);
      a2 += qh[j * 8 + 2] * b2f(ka[2]);
      a3 += qh[j * 8 + 3] * b2f(ka[3]);
      a0 += qh[j * 8 + 4] * b2f(ka[4]);
      a1 += qh[j * 8 + 5] * b2f(ka[5]);
      a2 += qh[j * 8 + 6] * b2f(ka[6]);
      a3 += qh[j * 8 + 7] * b2f(ka[7]);
    }
    float a = (a0 + a1) + (a2 + a3);
#endif
    if (a > m + 8.f) {
      float cs = __expf(m - a);
      sum *= cs;
#pragma unroll
      for (int dq = 0; dq < 16; ++dq) acc[dq] *= cs;
      m = a;
    }
    float p = __expf(a - m);
    sum += p;
#pragma unroll
    for (int dq = 0; dq < 16; ++dq)
      acc[dq] += p * *(const f32x4*)&Vs[s * 64 + dq * 4];
  }

  const int row = ob + t;
  msum[((size_t)side * NH + h) * Mc + row] = (float2){m, sum};
  u16* pp = (side ? part1 : part0) + (size_t)row * ND + h * 64;
#pragma unroll
  for (int j = 0; j < 8; ++j) {
    u16x8 o;
#pragma unroll
    for (int e = 0; e < 8; ++e) {
      int d = j * 8 + e;
      o[e] = f2b(acc[d >> 2][d & 3]);  // unnormalized partial
    }
    *(u16x8*)(pp + j * 8) = o;
  }
}

// ---------------------------------------------------------------------------
// Merge the two key-split partials -> normalized attn out, IN PLACE into
// part0. 256 threads = 2 rows per block (no barrier; per-half predication).
// ---------------------------------------------------------------------------
__global__ __launch_bounds__(256) void attn_merge_kernel(u16* __restrict__ part0,
                                                         const u16* __restrict__ part1,
                                                         const float2* __restrict__ msum,
                                                         const int* __restrict__ pMr,
                                                         int Mc) {
  const int t = threadIdx.x;
  const int r = blockIdx.x * 2 + (t >> 7);
  if (r >= *pMr) return;
  const int tt = t & 127;
  const int d0 = tt * 4;
  const int h = d0 >> 6;
  float2 s0 = msum[(size_t)h * Mc + r];
  float2 s1 = msum[((size_t)NH + h) * Mc + r];
  float newm = fmaxf(s0.x, s1.x);          // s0.x finite (side 0 has >=1 key)
  float cs0 = __expf(s0.x - newm);
  float cs1 = __expf(s1.x - newm);         // empty side 1: exp(-inf)=0
  float inv = 1.f / (s0.y * cs0 + s1.y * cs1);
  u16* p0 = part0 + (size_t)r * ND + d0;
  const u16* p1 = part1 + (size_t)r * ND + d0;
  u16x4 a = *(u16x4*)p0;
  u16x4 b = *(const u16x4*)p1;
  u16x4 o;
#pragma unroll
  for (int e = 0; e < 4; ++e)
    o[e] = f2b((b2f(a[e]) * cs0 + b2f(b[e]) * cs1) * inv);
  *(u16x4*)p0 = o;
}

// ---------------------------------------------------------------------------
// x = LN(x) * g + b IN-PLACE; writes bf16 mirror xb. VARLEN early-exit.
// ---------------------------------------------------------------------------
__global__ __launch_bounds__(128) void add_ln_kernel(float* __restrict__ x,
                                                     u16* __restrict__ xb,
                                                     const float* __restrict__ g,
                                                     const float* __restrict__ bb,
                                                     const int* __restrict__ pMr) {
  const int row = blockIdx.x;
  if (row >= *pMr) return;
  const int t = threadIdx.x;
  const size_t base = (size_t)row * ND + t * 4;
  float4 v = *(const float4*)(x + base);
  float s = (v.x + v.y) + (v.z + v.w);
  float q = (v.x * v.x + v.y * v.y) + (v.z * v.z + v.w * v.w);
#pragma unroll
  for (int off = 32; off; off >>= 1) {
    s += __shfl_down(s, off);
    q += __shfl_down(q, off);
  }
  __shared__ float sb[4];
  const int wid = t >> 6;
  if ((t & 63) == 0) { sb[wid * 2] = s; sb[wid * 2 + 1] = q; }
  __syncthreads();
  float ts = sb[0] + sb[2];
  float tq = sb[1] + sb[3];
  float mean = ts * (1.f / (float)ND);
  float var = tq * (1.f / (float)ND) - mean * mean;
  float rstd = rsqrtf(var + 1e-5f);
  float4 gg = *(const float4*)(g + t * 4);
  float4 bv = *(const float4*)(bb + t * 4);
  float o0 = (v.x - mean) * rstd * gg.x + bv.x;
  float o1 = (v.y - mean) * rstd * gg.y + bv.y;
  float o2 = (v.z - mean) * rstd * gg.z + bv.z;
  float o3 = (v.w - mean) * rstd * gg.w + bv.w;
  *(float4*)(x + base) = (float4){o0, o1, o2, o3};
  u16x4 ob = {f2b(o0), f2b(o1), f2b(o2), f2b(o3)};
  *(u16x4*)(xb + base) = ob;
}

// ---------------------------------------------------------------------------
// w2sum[d] = sum_o attn_w[o, D + d]   (s_q and attn_b cancel in the softmax)
// ---------------------------------------------------------------------------
__global__ __launch_bounds__(64) void w2sum_kernel(const float* __restrict__ attn_w,
                                                   float* __restrict__ w2sum) {
  int d = blockIdx.x * 64 + threadIdx.x;
  float s = 0.f;
  for (int o = 0; o < ND; ++o) s += attn_w[(size_t)o * 1024 + 512 + d];
  w2sum[d] = s;
}

// ---------------------------------------------------------------------------
// VARLEN pooling head, race-free (round-8 proven).
// ---------------------------------------------------------------------------
__global__ __launch_bounds__(256) void pool_kernel(const float* __restrict__ x,
                                                   const int* __restrict__ offs,
                                                   int BC,
                                                   const float* __restrict__ w2sum,
                                                   float* __restrict__ out) {
  const int b = blockIdx.x;
  const int c = b / BC;
  const int ob = offs[b] - offs[c * BC];
  const int len = offs[b + 1] - offs[b];  // >= 1
  const float* xr0 = x + ((size_t)c * BC * NS + ob) * ND;
  const int t = threadIdx.x;
  __shared__ float wsm[ND];
  __shared__ float sv[NS + 12];
  __shared__ float pv[256];
  __shared__ float red[8];
  wsm[t] = w2sum[t];
  wsm[t + 256] = w2sum[t + 256];
  __syncthreads();
  const int wv = t >> 6, ln = t & 63;
  for (int s = wv; s < len; s += 4) {
    const float* xr = xr0 + (size_t)s * ND;
    float acc = 0.f;
#pragma unroll
    for (int j = 0; j < 8; ++j) acc += xr[ln + j * 64] * wsm[ln + j * 64];
#pragma unroll
    for (int off = 32; off; off >>= 1) acc += __shfl_xor(acc, off);
    if (ln == 0) sv[s] = acc;
  }
  __syncthreads();
  float v = (t < len) ? sv[t] : -INFINITY;
  float m_ = v;
#pragma unroll
  for (int off = 32; off; off >>= 1) m_ = fmaxf(m_, __shfl_xor(m_, off));
  if (ln == 0) red[wv] = m_;
  __syncthreads();
  const float mx = fmaxf(fmaxf(red[0], red[1]), fmaxf(red[2], red[3]));
  float e = (t < len) ? __expf(v - mx) : 0.f;
  pv[t] = e;
  float s_ = e;
#pragma unroll
  for (int off = 32; off; off >>= 1) s_ += __shfl_xor(s_, off);
  if (ln == 0) red[4 + wv] = s_;
  __syncthreads();
  const float inv = 1.f / ((red[4] + red[5]) + (red[6] + red[7]));
  float a0 = 0.f, a1 = 0.f;
  for (int s = 0; s < len; ++s) {
    float p = pv[s];
    const float* xr = xr0 + (size_t)s * ND;
    a0 += p * xr[t];
    a1 += p * xr[t + 256];
  }
  out[(size_t)b * ND + t] = a0 * inv;
  out[(size_t)b * ND + t + 256] = a1 * inv;
}

// ---------------------------------------------------------------------------
extern "C" void kernel_launch(void* const* d_in, const int* in_sizes, int n_in,
                              void* d_out, int out_size, void* d_ws, size_t ws_size,
                              hipStream_t stream) {
  const int* mask = (const int*)d_in[0];
  const float* emb = (const float*)d_in[1];
  const float* in_proj_w = (const float*)d_in[2];
  const float* in_proj_b = (const float*)d_in[3];
  const float* out_proj_w = (const float*)d_in[4];
  const float* out_proj_b = (const float*)d_in[5];
  const float* lin1_w = (const float*)d_in[6];
  const float* lin1_b = (const float*)d_in[7];
  const float* lin2_w = (const float*)d_in[8];
  const float* lin2_b = (const float*)d_in[9];
  const float* ln1_w = (const float*)d_in[10];
  const float* ln1_b = (const float*)d_in[11];
  const float* ln2_w = (const float*)d_in[12];
  const float* ln2_b = (const float*)d_in[13];
  const float* attn_w = (const float*)d_in[14];
  // d_in[15] = attn_b: constant over softmax axis -> cancels; unused.

  char* wsb = (char*)d_ws;
  size_t off = 0;
  auto alloc = [&](size_t bytes) -> char* {
    char* p = wsb + off;
    off += (bytes + 255) & ~(size_t)255;
    return p;
  };
  float* x   = (float*)alloc((size_t)NM * ND * 4);   // compacted, chunk-strided
  u16* xb    = (u16*)alloc((size_t)NM * ND * 2);     // compacted bf16 mirror
  u16* wqkv  = (u16*)alloc((size_t)NL * 1536 * 512 * 2);
  u16* wout  = (u16*)alloc((size_t)NL * 512 * 512 * 2);
  u16* w1b   = (u16*)alloc((size_t)NL * 2048 * 512 * 2);
  u16* w2b   = (u16*)alloc((size_t)NL * 512 * 2048 * 2);
  float* w2s = (float*)alloc(ND * 4);
  int* offs  = (int*)alloc((NB + 1) * 4);
  int* meta  = (int*)alloc(16 * 4);   // Mr per chunk (<= 8 chunks)
  int* order = (int*)alloc(NB * 4);   // LPT batch order per chunk
  size_t fixedEnd = off;

  int BC = 32;
  const int cands[4] = {256, 128, 64, 32};
  auto alup = [](size_t b) { return (b + 255) & ~(size_t)255; };
  for (int ci = 0; ci < 4; ++ci) {
    size_t Mc = (size_t)cands[ci] * NS;
    if (fixedEnd + alup(Mc * 2048 * 2) <= ws_size) { BC = cands[ci]; break; }
  }
  const size_t Mc = (size_t)BC * NS;
  const int NC = NB / BC;
  u16* big  = (u16*)alloc(Mc * 2048 * 2);   // qkv (Mc x 1536) / h1 (Mc x 2048)
  u16* attO = big + Mc * 1536;              // attn out / split part0 (Mc x 512)

  // Key-split extras (engage only if workspace fits)
  size_t needP1 = alup(Mc * 512 * 2);
  size_t needMS = alup(2 * NH * Mc * 8);
  bool splitOK = (off + needP1 + needMS <= ws_size);
  u16* part1 = nullptr;
  float2* msum = nullptr;
  if (splitOK) {
    part1 = (u16*)alloc(Mc * 512 * 2);
    msum = (float2*)alloc(2 * NH * Mc * 8);
  }

  cast_kernel<<<NL * 1536 * 512 / 1024, 256, 0, stream>>>(in_proj_w, wqkv);
  cast_kernel<<<NL * 512 * 512 / 1024, 256, 0, stream>>>(out_proj_w, wout);
  cast_kernel<<<NL * 2048 * 512 / 1024, 256, 0, stream>>>(lin1_w, w1b);
  cast_kernel<<<NL * 512 * 2048 / 1024, 256, 0, stream>>>(lin2_w, w2b);
  scan_kernel<<<1, 256, 0, stream>>>(mask, offs, meta, order, BC, NC);
  pe_compact_kernel<<<NM, 128, 0, stream>>>(emb, offs, BC, x, xb);

  for (int i = 0; i < NL; ++i) {
    for (int c = 0; c < NC; ++c) {
      float* xc = x + (size_t)c * Mc * ND;
      u16* xbc = xb + (size_t)c * Mc * ND;
      const int* pMr = meta + c;
      gemm_mfma<128, false, true, false><<<dim3(1536 / 128, Mc / 128), 256, 0, stream>>>(
          xbc, wqkv + (size_t)i * 1536 * 512, in_proj_b + i * 1536, nullptr, nullptr, big, pMr, 1536, 512);
      if (splitOK) {
        attn_split_kernel<<<BC * NH * 2, 128, 0, stream>>>(
            big, offs, order, c * BC, (int)Mc, attO, part1, msum);
        attn_merge_kernel<<<Mc / 2, 256, 0, stream>>>(attO, part1, msum, pMr, (int)Mc);
      } else {
        attn_kernel<<<BC * NH, 128, 0, stream>>>(big, offs, order, c * BC, attO);
      }
      gemm_mfma<64, false, false, true><<<dim3(512 / 128, Mc / 64), 256, 0, stream>>>(
          attO, wout + (size_t)i * 512 * 512, out_proj_b + i * 512, xc, xc, nullptr, pMr, 512, 512);
      add_ln_kernel<<<Mc, 128, 0, stream>>>(xc, xbc, ln1_w + i * 512, ln1_b + i * 512, pMr);
      gemm_mfma<128, true, true, false><<<dim3(2048 / 128, Mc / 128), 256, 0, stream>>>(
          xbc, w1b + (size_t)i * 2048 * 512, lin1_b + i * 2048, nullptr, nullptr, big, pMr, 2048, 512);
      gemm_mfma<64, false, false, true><<<dim3(512 / 128, Mc / 64), 256, 0, stream>>>(
          big, w2b + (size_t)i * 512 * 2048, lin2_b + i * 512, xc, xc, nullptr, pMr, 512, 2048);
      add_ln_kernel<<<Mc, 128, 0, stream>>>(xc, xbc, ln2_w + i * 512, ln2_b + i * 512, pMr);
    }
  }

  w2sum_kernel<<<ND / 64, 64, 0, stream>>>(attn_w, w2s);
  pool_kernel<<<NB, 256, 0, stream>>>(x, offs, BC, w2s, (float*)d_out);
}

// Round 21
// 1078.341 us; speedup vs baseline: 1.0064x; 1.0064x over previous
//
#include <hip/hip_runtime.h>
#include <math.h>

#define NB 256
#define NS 100
#define ND 512
#define NH 8
#define NDFF 2048
#define NL 4
#define NM (NB * NS)  // 25600 tokens

typedef unsigned short u16;
typedef unsigned short u16x4 __attribute__((ext_vector_type(4)));
typedef unsigned short u16x8 __attribute__((ext_vector_type(8)));
typedef __bf16 bf16x8 __attribute__((ext_vector_type(8)));
typedef float f32x4 __attribute__((ext_vector_type(4)));
typedef _Float16 f16x2 __attribute__((ext_vector_type(2)));
typedef _Float16 f16x8 __attribute__((ext_vector_type(8)));

#if __has_builtin(__builtin_amdgcn_fdot2)
#define USE_FDOT2 1
#else
#define USE_FDOT2 0
#endif

__device__ __forceinline__ float b2f(u16 u) {
  unsigned v = ((unsigned)u) << 16;
  return __builtin_bit_cast(float, v);
}
__device__ __forceinline__ u16 f2b(float f) {
  unsigned u = __builtin_bit_cast(unsigned, f);
  u += 0x7fffu + ((u >> 16) & 1u);
  return (u16)(u >> 16);
}
// async global->LDS, 16B per lane; LDS dest is wave-uniform base (HW adds lane*16)
__device__ __forceinline__ void gload_lds16(const void* g, void* l) {
  __builtin_amdgcn_global_load_lds(
      (const __attribute__((address_space(1))) unsigned int*)g,
      (__attribute__((address_space(3))) unsigned int*)l, 16, 0, 0);
}

// ---------------------------------------------------------------------------
// f32 -> bf16 cast (weights)
// ---------------------------------------------------------------------------
__global__ __launch_bounds__(256) void cast_kernel(const float* __restrict__ in,
                                                   u16* __restrict__ out) {
  int i = blockIdx.x * 256 + threadIdx.x;
  float4 v = ((const float4*)in)[i];
  u16x4 o = {f2b(v.x), f2b(v.y), f2b(v.z), f2b(v.w)};
  ((u16x4*)out)[i] = o;
}

// ---------------------------------------------------------------------------
// Per-batch lengths (prefix mask) + exclusive scan + per-chunk token counts
// + LPT schedule order (descending len, index tie-break). Results-invariant.
// ---------------------------------------------------------------------------
__global__ __launch_bounds__(256) void scan_kernel(const int* __restrict__ mask,
                                                   int* __restrict__ offs,
                                                   int* __restrict__ meta,
                                                   int* __restrict__ order,
                                                   int BC, int NC) {
  const int b = threadIdx.x;
  const int* mp = mask + b * NS;
  int len = 0;
#pragma unroll
  for (int i = 0; i < NS; i += 4) {
    int4 v = *(const int4*)(mp + i);
    len += v.x + v.y + v.z + v.w;
  }
  int v = len;
#pragma unroll
  for (int off = 1; off < 64; off <<= 1) {
    int u = __shfl_up(v, off);
    if ((b & 63) >= off) v += u;
  }
  __shared__ int wsum[4];
  __shared__ int incl[256];
  __shared__ int slen[256];
  slen[b] = len;
  if ((b & 63) == 63) wsum[b >> 6] = v;
  __syncthreads();
  int add = 0;
  for (int w = 0; w < (b >> 6); ++w) add += wsum[w];
  v += add;
  incl[b] = v;
  offs[b + 1] = v;
  if (b == 0) offs[0] = 0;
  __syncthreads();
  if (b < NC) meta[b] = incl[(b + 1) * BC - 1] - (b ? incl[b * BC - 1] : 0);
  // LPT rank within this batch's chunk (descending len, unique via idx tie)
  const int c0 = (b / BC) * BC;
  int rank = 0;
  for (int j = c0; j < c0 + BC; ++j)
    rank += (slen[j] > len) || (slen[j] == len && j < b);
  order[c0 + rank] = b;
}

// ---------------------------------------------------------------------------
// Fused PE-add + COMPACTION gather: real token (b,s) -> compacted row of its
// chunk. One block per source token; padded tokens exit (prefix mask).
// ---------------------------------------------------------------------------
__global__ __launch_bounds__(128) void pe_compact_kernel(const float* __restrict__ emb,
                                                         const int* __restrict__ offs,
                                                         int BC,
                                                         float* __restrict__ x,
                                                         u16* __restrict__ xb) {
  const int tok = blockIdx.x;
  const int b = tok / NS, s = tok - b * NS;
  const int ob = offs[b];
  const int len = offs[b + 1] - ob;
  if (s >= len) return;
  const int c = b / BC;
  const size_t dst = ((size_t)c * BC * NS + (ob - offs[c * BC]) + s) * ND;
  const int t = threadIdx.x;
  const int d0 = t * 4;
  float4 ev = *(const float4*)(emb + (size_t)tok * ND + d0);
  float o[4];
#pragma unroll
  for (int e = 0; e < 4; ++e) {
    int d = d0 + e;
    float ang = (float)s * (float)(d & ~1) * (-4.6051701859880914f / (float)ND);
    float pe = (d & 1) ? __cosf(ang) : __sinf(ang);
    o[e] = ((const float*)&ev)[e] + pe;
  }
  *(float4*)(x + dst + d0) = (float4){o[0], o[1], o[2], o[3]};
  u16x4 ob16 = {f2b(o[0]), f2b(o[1]), f2b(o[2]), f2b(o[3])};
  *(u16x4*)(xb + dst + d0) = ob16;
}

// ---------------------------------------------------------------------------
// C = A @ W^T + bias (+R residual) (optional ReLU). A: MxK bf16, W: NxK bf16.
// TM x 128 tile (TM=128 or 64), BK=64, 4 waves. Linear LDS via global_load_lds
// w/ pre-swizzled source; ds_read applies blk ^= (row&7) -> conflict-free.
// Round-13/14 PROVEN epilogue. RESID may be IN-PLACE (R == Cf).
// VARLEN early-exit beyond round-up-TM(*pMr).
// C/D: col = lane&15, row = (lane>>4)*4 + j   [verified rounds 2-20]
// ---------------------------------------------------------------------------
template <int TM, bool RELU, bool OUTBF16, bool RESID>
__global__ __launch_bounds__(256) void gemm_mfma(const u16* __restrict__ A,
                                                 const u16* __restrict__ W,
                                                 const float* __restrict__ bias,
                                                 const float* __restrict__ R,
                                                 float* __restrict__ Cf,
                                                 u16* __restrict__ Cb,
                                                 const int* __restrict__ pMr,
                                                 int N, int K) {
  constexpr int MF = TM / 32;  // m-fragments per wave (wave rows = 16*MF)
  const int m0 = blockIdx.y * TM, n0 = blockIdx.x * 128;
  if (m0 >= ((*pMr + TM - 1) & ~(TM - 1))) return;  // uniform early-exit
  __shared__ u16 As[TM * 64];
  __shared__ u16 Ws[128 * 64];
  const int t = threadIdx.x;
  const int lane = t & 63;
  const int wave = t >> 6;
  const int wr = wave >> 1, wc = wave & 1;
  const int srow = lane >> 3;
  const int sblk = (lane & 7) ^ srow;
  const u16* gA = A + (size_t)(m0 + wave * 8 + srow) * K + sblk * 8;
  const u16* gW = W + (size_t)(n0 + wave * 8 + srow) * K + sblk * 8;
  u16* lA = As + wave * 512;
  u16* lW = Ws + wave * 512;
  f32x4 acc[MF][4];
#pragma unroll
  for (int m = 0; m < MF; ++m)
#pragma unroll
    for (int n = 0; n < 4; ++n) acc[m][n] = (f32x4){0.f, 0.f, 0.f, 0.f};
  const int lg = lane >> 4;
  const int li = lane & 15;
  const int l7 = li & 7;
  for (int k0 = 0; k0 < K; k0 += 64) {
    __syncthreads();
#pragma unroll
    for (int i = 0; i < MF; ++i)
      gload_lds16(gA + k0 + (size_t)(32 * i) * K, lA + i * 2048);
#pragma unroll
    for (int i = 0; i < 4; ++i)
      gload_lds16(gW + k0 + (size_t)(32 * i) * K, lW + i * 2048);
    __syncthreads();
#pragma unroll
    for (int h = 0; h < 2; ++h) {
      bf16x8 af[MF], bf_[4];
#pragma unroll
      for (int m = 0; m < MF; ++m) {
        int row = wr * (16 * MF) + m * 16 + li;
        af[m] = __builtin_bit_cast(
            bf16x8, *(const u16x8*)&As[row * 64 + (((h << 2) + lg) ^ l7) * 8]);
      }
#pragma unroll
      for (int n = 0; n < 4; ++n) {
        int row = wc * 64 + n * 16 + li;
        bf_[n] = __builtin_bit_cast(
            bf16x8, *(const u16x8*)&Ws[row * 64 + (((h << 2) + lg) ^ l7) * 8]);
      }
#pragma unroll
      for (int m = 0; m < MF; ++m)
#pragma unroll
        for (int n = 0; n < 4; ++n)
          acc[m][n] = __builtin_amdgcn_mfma_f32_16x16x32_bf16(af[m], bf_[n], acc[m][n], 0, 0, 0);
    }
  }
#pragma unroll
  for (int m = 0; m < MF; ++m) {
    int row = m0 + wr * (16 * MF) + m * 16 + lg * 4;
#pragma unroll
    for (int n = 0; n < 4; ++n) {
      int col = n0 + wc * 64 + n * 16 + li;
      float bv = bias[col];
#pragma unroll
      for (int j = 0; j < 4; ++j) {
        float v = acc[m][n][j] + bv;
        if (RESID) v += R[(size_t)(row + j) * N + col];
        if (RELU) v = fmaxf(v, 0.f);
        if (OUTBF16) Cb[(size_t)(row + j) * N + col] = f2b(v);
        else Cf[(size_t)(row + j) * N + col] = v;
      }
    }
  }
}

// ---------------------------------------------------------------------------
// Q-register load helpers (f16 pairs when fdot2 available).
// ---------------------------------------------------------------------------
#if USE_FDOT2
#define QREGS f16x2 qh[32]
#define LOADQ(gq)                                   \
  _Pragma("unroll") for (int j = 0; j < 8; ++j) {   \
    u16x8 qq = *(const u16x8*)((gq) + j * 8);       \
    _Pragma("unroll") for (int e = 0; e < 4; ++e) { \
      f16x2 p;                                      \
      p[0] = (_Float16)b2f(qq[e * 2 + 0]);          \
      p[1] = (_Float16)b2f(qq[e * 2 + 1]);          \
      qh[j * 4 + e] = p;                            \
    }                                               \
  }
#else
#define QREGS float qh[64]
#define LOADQ(gq)                                   \
  _Pragma("unroll") for (int j = 0; j < 8; ++j) {   \
    u16x8 qq = *(const u16x8*)((gq) + j * 8);       \
    _Pragma("unroll") for (int e = 0; e < 8; ++e)   \
      qh[j * 8 + e] = b2f(qq[e]) * 0.125f;          \
  }
#endif

// ---------------------------------------------------------------------------
// VARLEN attention, SINGLE-pass fallback (round-13 proven, 38.4 KB LDS).
// ---------------------------------------------------------------------------
__global__ __launch_bounds__(128) void attn_kernel(const u16* __restrict__ qkv,
                                                   const int* __restrict__ offs,
                                                   const int* __restrict__ order,
                                                   int bBase,
                                                   u16* __restrict__ out) {
  const int bh = blockIdx.x;
  const int bl = bh >> 3, h = bh & 7;
  const int bg = order[bBase + bl];       // LPT order (results-invariant)
  const int ob = offs[bg] - offs[bBase];
  const int len = offs[bg + 1] - offs[bg];  // >= 1
  __shared__ u16 Ksb[NS * 64];
  __shared__ float Vs[NS * 64];
  const int t = threadIdx.x;
  const u16* base = qkv + (size_t)ob * 1536 + h * 64;

  for (int e = t; e < len * 16; e += 128) {
    int s = e >> 4, d4 = (e & 15) << 2;
    u16x4 kk = *(const u16x4*)(base + (size_t)s * 1536 + 512 + d4);
#if USE_FDOT2
    u16x4 kh;
#pragma unroll
    for (int q = 0; q < 4; ++q) {
      _Float16 hv = (_Float16)b2f(kk[q]);
      kh[q] = __builtin_bit_cast(u16, hv);
    }
    *(u16x4*)&Ksb[s * 64 + d4] = kh;
#else
    *(u16x4*)&Ksb[s * 64 + d4] = kk;
#endif
    u16x4 vv = *(const u16x4*)(base + (size_t)s * 1536 + 1024 + d4);
    Vs[s * 64 + d4 + 0] = b2f(vv[0]);
    Vs[s * 64 + d4 + 1] = b2f(vv[1]);
    Vs[s * 64 + d4 + 2] = b2f(vv[2]);
    Vs[s * 64 + d4 + 3] = b2f(vv[3]);
  }
  QREGS;
  if (t < len) { LOADQ(base + (size_t)t * 1536); }
  __syncthreads();
  if (t >= len) return;

  f32x4 acc[16];
#pragma unroll
  for (int dq = 0; dq < 16; ++dq) acc[dq] = (f32x4){0.f, 0.f, 0.f, 0.f};
  float m = -INFINITY, sum = 0.f;
  int s = 0;
  for (; s + 2 <= len; s += 2) {
    float a0 = 0.f, a1 = 0.f, a2 = 0.f, a3 = 0.f;
    float c0 = 0.f, c1 = 0.f, c2 = 0.f, c3 = 0.f;
#if USE_FDOT2
#pragma unroll
    for (int j = 0; j < 8; ++j) {
      f16x8 ka = __builtin_bit_cast(f16x8, *(const u16x8*)&Ksb[s * 64 + j * 8]);
      f16x8 kb = __builtin_bit_cast(f16x8, *(const u16x8*)&Ksb[(s + 1) * 64 + j * 8]);
      f16x2 ka0 = {ka[0], ka[1]}, ka1 = {ka[2], ka[3]};
      f16x2 ka2 = {ka[4], ka[5]}, ka3 = {ka[6], ka[7]};
      f16x2 kb0 = {kb[0], kb[1]}, kb1 = {kb[2], kb[3]};
      f16x2 kb2 = {kb[4], kb[5]}, kb3 = {kb[6], kb[7]};
      a0 = __builtin_amdgcn_fdot2(qh[j * 4 + 0], ka0, a0, false);
      c0 = __builtin_amdgcn_fdot2(qh[j * 4 + 0], kb0, c0, false);
      a1 = __builtin_amdgcn_fdot2(qh[j * 4 + 1], ka1, a1, false);
      c1 = __builtin_amdgcn_fdot2(qh[j * 4 + 1], kb1, c1, false);
      a2 = __builtin_amdgcn_fdot2(qh[j * 4 + 2], ka2, a2, false);
      c2 = __builtin_amdgcn_fdot2(qh[j * 4 + 2], kb2, c2, false);
      a3 = __builtin_amdgcn_fdot2(qh[j * 4 + 3], ka3, a3, false);
      c3 = __builtin_amdgcn_fdot2(qh[j * 4 + 3], kb3, c3, false);
    }
    float a = ((a0 + a1) + (a2 + a3)) * 0.125f;
    float c = ((c0 + c1) + (c2 + c3)) * 0.125f;
#else
#pragma unroll
    for (int j = 0; j < 8; ++j) {
      u16x8 ka = *(const u16x8*)&Ksb[s * 64 + j * 8];
      u16x8 kb = *(const u16x8*)&Ksb[(s + 1) * 64 + j * 8];
      a0 += qh[j * 8 + 0] * b2f(ka[0]); c0 += qh[j * 8 + 0] * b2f(kb[0]);
      a1 += qh[j * 8 + 1] * b2f(ka[1]); c1 += qh[j * 8 + 1] * b2f(kb[1]);
      a2 += qh[j * 8 + 2] * b2f(ka[2]); c2 += qh[j * 8 + 2] * b2f(kb[2]);
      a3 += qh[j * 8 + 3] * b2f(ka[3]); c3 += qh[j * 8 + 3] * b2f(kb[3]);
      a0 += qh[j * 8 + 4] * b2f(ka[4]); c0 += qh[j * 8 + 4] * b2f(kb[4]);
      a1 += qh[j * 8 + 5] * b2f(ka[5]); c1 += qh[j * 8 + 5] * b2f(kb[5]);
      a2 += qh[j * 8 + 6] * b2f(ka[6]); c2 += qh[j * 8 + 6] * b2f(kb[6]);
      a3 += qh[j * 8 + 7] * b2f(ka[7]); c3 += qh[j * 8 + 7] * b2f(kb[7]);
    }
    float a = (a0 + a1) + (a2 + a3);
    float c = (c0 + c1) + (c2 + c3);
#endif
    float mx2 = fmaxf(a, c);
    if (mx2 > m + 8.f) {
      float cs = __expf(m - mx2);
      sum *= cs;
#pragma unroll
      for (int dq = 0; dq < 16; ++dq) acc[dq] *= cs;
      m = mx2;
    }
    float pa = __expf(a - m);
    float pc = __expf(c - m);
    sum += pa + pc;
#pragma unroll
    for (int dq = 0; dq < 16; ++dq) {
      f32x4 va = *(const f32x4*)&Vs[s * 64 + dq * 4];
      f32x4 vb = *(const f32x4*)&Vs[(s + 1) * 64 + dq * 4];
      acc[dq] += pa * va + pc * vb;
    }
  }
  if (s < len) {
    float a0 = 0.f, a1 = 0.f, a2 = 0.f, a3 = 0.f;
#if USE_FDOT2
#pragma unroll
    for (int j = 0; j < 8; ++j) {
      f16x8 ka = __builtin_bit_cast(f16x8, *(const u16x8*)&Ksb[s * 64 + j * 8]);
      f16x2 ka0 = {ka[0], ka[1]}, ka1 = {ka[2], ka[3]};
      f16x2 ka2 = {ka[4], ka[5]}, ka3 = {ka[6], ka[7]};
      a0 = __builtin_amdgcn_fdot2(qh[j * 4 + 0], ka0, a0, false);
      a1 = __builtin_amdgcn_fdot2(qh[j * 4 + 1], ka1, a1, false);
      a2 = __builtin_amdgcn_fdot2(qh[j * 4 + 2], ka2, a2, false);
      a3 = __builtin_amdgcn_fdot2(qh[j * 4 + 3], ka3, a3, false);
    }
    float a = ((a0 + a1) + (a2 + a3)) * 0.125f;
#else
#pragma unroll
    for (int j = 0; j < 8; ++j) {
      u16x8 ka = *(const u16x8*)&Ksb[s * 64 + j * 8];
      a0 += qh[j * 8 + 0] * b2f(ka[0]);
      a1 += qh[j * 8 + 1] * b2f(ka[1]);
      a2 += qh[j * 8 + 2] * b2f(ka[2]);
      a3 += qh[j * 8 + 3] * b2f(ka[3]);
      a0 += qh[j * 8 + 4] * b2f(ka[4]);
      a1 += qh[j * 8 + 5] * b2f(ka[5]);
      a2 += qh[j * 8 + 6] * b2f(ka[6]);
      a3 += qh[j * 8 + 7] * b2f(ka[7]);
    }
    float a = (a0 + a1) + (a2 + a3);
#endif
    if (a > m + 8.f) {
      float cs = __expf(m - a);
      sum *= cs;
#pragma unroll
      for (int dq = 0; dq < 16; ++dq) acc[dq] *= cs;
      m = a;
    }
    float p = __expf(a - m);
    sum += p;
#pragma unroll
    for (int dq = 0; dq < 16; ++dq)
      acc[dq] += p * *(const f32x4*)&Vs[s * 64 + dq * 4];
  }
  float inv = 1.f / sum;
  u16* op = out + (size_t)(ob + t) * ND + h * 64;
#pragma unroll
  for (int j = 0; j < 8; ++j) {
    u16x8 o;
#pragma unroll
    for (int e = 0; e < 8; ++e) {
      int d = j * 8 + e;
      o[e] = f2b(acc[d >> 2][d & 3] * inv);
    }
    *(u16x8*)(op + j * 8) = o;
  }
}

// ---------------------------------------------------------------------------
// VARLEN attention, KEY-SPLIT (grid.y = side in {0,1}); LDS 19.3 KB.
// [r20 A/B: interleaving side into the low grid bit raised FETCH_SIZE
// 21.8->26.3 MB (lost L2 locality between neighboring same-side blocks)
// and was net-neutral/-5us. 2-D grid (all side-0 first) restored.]
// f32 V (r17 A/B). LPT order via order[] (r19, +18us win).
// ---------------------------------------------------------------------------
#define KHALF 50
__global__ __launch_bounds__(128) void attn_split_kernel(const u16* __restrict__ qkv,
                                                         const int* __restrict__ offs,
                                                         const int* __restrict__ order,
                                                         int bBase, int Mc,
                                                         u16* __restrict__ part0,
                                                         u16* __restrict__ part1,
                                                         float2* __restrict__ msum) {
  const int bh = blockIdx.x;
  const int side = blockIdx.y;
  const int bl = bh >> 3, h = bh & 7;
  const int bg = order[bBase + bl];       // LPT order (results-invariant)
  const int ob = offs[bg] - offs[bBase];
  const int len = offs[bg + 1] - offs[bg];  // >= 1
  const int hl = (len + 1) >> 1;
  const int k0 = side ? hl : 0;
  const int k1 = side ? len : hl;
  const int nk = k1 - k0;  // side 0: >=1, side 1: may be 0
  __shared__ u16 Ksb[KHALF * 64];   // 6.4 KB
  __shared__ float Vs[KHALF * 64];  // 12.8 KB
  const int t = threadIdx.x;
  const u16* baseQ = qkv + (size_t)ob * 1536 + h * 64;
  const u16* baseK = baseQ + (size_t)k0 * 1536;

  for (int e = t; e < nk * 16; e += 128) {
    int s = e >> 4, d4 = (e & 15) << 2;
    u16x4 kk = *(const u16x4*)(baseK + (size_t)s * 1536 + 512 + d4);
#if USE_FDOT2
    u16x4 kh;
#pragma unroll
    for (int q = 0; q < 4; ++q) {
      _Float16 hv = (_Float16)b2f(kk[q]);
      kh[q] = __builtin_bit_cast(u16, hv);
    }
    *(u16x4*)&Ksb[s * 64 + d4] = kh;
#else
    *(u16x4*)&Ksb[s * 64 + d4] = kk;
#endif
    u16x4 vv = *(const u16x4*)(baseK + (size_t)s * 1536 + 1024 + d4);
    Vs[s * 64 + d4 + 0] = b2f(vv[0]);
    Vs[s * 64 + d4 + 1] = b2f(vv[1]);
    Vs[s * 64 + d4 + 2] = b2f(vv[2]);
    Vs[s * 64 + d4 + 3] = b2f(vv[3]);
  }
  QREGS;
  if (t < len) { LOADQ(baseQ + (size_t)t * 1536); }
  __syncthreads();
  if (t >= len) return;

  f32x4 acc[16];
#pragma unroll
  for (int dq = 0; dq < 16; ++dq) acc[dq] = (f32x4){0.f, 0.f, 0.f, 0.f};
  float m = -INFINITY, sum = 0.f;
  int s = 0;
  for (; s + 2 <= nk; s += 2) {
    float a0 = 0.f, a1 = 0.f, a2 = 0.f, a3 = 0.f;
    float c0 = 0.f, c1 = 0.f, c2 = 0.f, c3 = 0.f;
#if USE_FDOT2
#pragma unroll
    for (int j = 0; j < 8; ++j) {
      f16x8 ka = __builtin_bit_cast(f16x8, *(const u16x8*)&Ksb[s * 64 + j * 8]);
      f16x8 kb = __builtin_bit_cast(f16x8, *(const u16x8*)&Ksb[(s + 1) * 64 + j * 8]);
      f16x2 ka0 = {ka[0], ka[1]}, ka1 = {ka[2], ka[3]};
      f16x2 ka2 = {ka[4], ka[5]}, ka3 = {ka[6], ka[7]};
      f16x2 kb0 = {kb[0], kb[1]}, kb1 = {kb[2], kb[3]};
      f16x2 kb2 = {kb[4], kb[5]}, kb3 = {kb[6], kb[7]};
      a0 = __builtin_amdgcn_fdot2(qh[j * 4 + 0], ka0, a0, false);
      c0 = __builtin_amdgcn_fdot2(qh[j * 4 + 0], kb0, c0, false);
      a1 = __builtin_amdgcn_fdot2(qh[j * 4 + 1], ka1, a1, false);
      c1 = __builtin_amdgcn_fdot2(qh[j * 4 + 1], kb1, c1, false);
      a2 = __builtin_amdgcn_fdot2(qh[j * 4 + 2], ka2, a2, false);
      c2 = __builtin_amdgcn_fdot2(qh[j * 4 + 2], kb2, c2, false);
      a3 = __builtin_amdgcn_fdot2(qh[j * 4 + 3], ka3, a3, false);
      c3 = __builtin_amdgcn_fdot2(qh[j * 4 + 3], kb3, c3, false);
    }
    float a = ((a0 + a1) + (a2 + a3)) * 0.125f;
    float c = ((c0 + c1) + (c2 + c3)) * 0.125f;
#else
#pragma unroll
    for (int j = 0; j < 8; ++j) {
      u16x8 ka = *(const u16x8*)&Ksb[s * 64 + j * 8];
      u16x8 kb = *(const u16x8*)&Ksb[(s + 1) * 64 + j * 8];
      a0 += qh[j * 8 + 0] * b2f(ka[0]); c0 += qh[j * 8 + 0] * b2f(kb[0]);
      a1 += qh[j * 8 + 1] * b2f(ka[1]); c1 += qh[j * 8 + 1] * b2f(kb[1]);
      a2 += qh[j * 8 + 2] * b2f(ka[2]); c2 += qh[j * 8 + 2] * b2f(kb[2]);
      a3 += qh[j * 8 + 3] * b2f(ka[3]); c3 += qh[j * 8 + 3] * b2f(kb[3]);
      a0 += qh[j * 8 + 4] * b2f(ka[4]); c0 += qh[j * 8 + 4] * b2f(kb[4]);
      a1 += qh[j * 8 + 5] * b2f(ka[5]); c1 += qh[j * 8 + 5] * b2f(kb[5]);
      a2 += qh[j * 8 + 6] * b2f(ka[6]); c2 += qh[j * 8 + 6] * b2f(kb[6]);
      a3 += qh[j * 8 + 7] * b2f(ka[7]); c3 += qh[j * 8 + 7] * b2f(kb[7]);
    }
    float a = (a0 + a1) + (a2 + a3);
    float c = (c0 + c1) + (c2 + c3);
#endif
    float mx2 = fmaxf(a, c);
    if (mx2 > m + 8.f) {
      float cs = __expf(m - mx2);
      sum *= cs;
#pragma unroll
      for (int dq = 0; dq < 16; ++dq) acc[dq] *= cs;
      m = mx2;
    }
    float pa = __expf(a - m);
    float pc = __expf(c - m);
    sum += pa + pc;
#pragma unroll
    for (int dq = 0; dq < 16; ++dq) {
      f32x4 va = *(const f32x4*)&Vs[s * 64 + dq * 4];
      f32x4 vb = *(const f32x4*)&Vs[(s + 1) * 64 + dq * 4];
      acc[dq] += pa * va + pc * vb;
    }
  }
  if (s < nk) {
    float a0 = 0.f, a1 = 0.f, a2 = 0.f, a3 = 0.f;
#if USE_FDOT2
#pragma unroll
    for (int j = 0; j < 8; ++j) {
      f16x8 ka = __builtin_bit_cast(f16x8, *(const u16x8*)&Ksb[s * 64 + j * 8]);
      f16x2 ka0 = {ka[0], ka[1]}, ka1 = {ka[2], ka[3]};
      f16x2 ka2 = {ka[4], ka[5]}, ka3 = {ka[6], ka[7]};
      a0 = __builtin_amdgcn_fdot2(qh[j * 4 + 0], ka0, a0, false);
      a1 = __builtin_amdgcn_fdot2(qh[j * 4 + 1], ka1, a1, false);
      a2 = __builtin_amdgcn_fdot2(qh[j * 4 + 2], ka2, a2, false);
      a3 = __builtin_amdgcn_fdot2(qh[j * 4 + 3], ka3, a3, false);
    }
    float a = ((a0 + a1) + (a2 + a3)) * 0.125f;
#else
#pragma unroll
    for (int j = 0; j < 8; ++j) {
      u16x8 ka = *(const u16x8*)&Ksb[s * 64 + j * 8];
      a0 += qh[j * 8 + 0] * b2f(ka[0]);
      a1 += qh[j * 8 + 1] * b2f(ka[1]);
      a2 += qh[j * 8 + 2] * b2f(ka[2]);
      a3 += qh[j * 8 + 3] * b2f(ka[3]);
      a0 += qh[j * 8 + 4] * b2f(ka[4]);
      a1 += qh[j * 8 + 5] * b2f(ka[5]);
      a2 += qh[j * 8 + 6] * b2f(ka[6]);
      a3 += qh[j * 8 + 7] * b2f(ka[7]);
    }
    float a = (a0 + a1) + (a2 + a3);
#endif
    if (a > m + 8.f) {
      float cs = __expf(m - a);
      sum *= cs;
#pragma unroll
      for (int dq = 0; dq < 16; ++dq) acc[dq] *= cs;
      m = a;
    }
    float p = __expf(a - m);
    sum += p;
#pragma unroll
    for (int dq = 0; dq < 16; ++dq)
      acc[dq] += p * *(const f32x4*)&Vs[s * 64 + dq * 4];
  }

  const int row = ob + t;
  msum[((size_t)side * NH + h) * Mc + row] = (float2){m, sum};
  u16* pp = (side ? part1 : part0) + (size_t)row * ND + h * 64;
#pragma unroll
  for (int j = 0; j < 8; ++j) {
    u16x8 o;
#pragma unroll
    for (int e = 0; e < 8; ++e) {
      int d = j * 8 + e;
      o[e] = f2b(acc[d >> 2][d & 3]);  // unnormalized partial
    }
    *(u16x8*)(pp + j * 8) = o;
  }
}

// ---------------------------------------------------------------------------
// Merge the two key-split partials -> normalized attn out, IN PLACE into
// part0. 256 threads = 2 rows per block (no barrier; per-half predication).
// ---------------------------------------------------------------------------
__global__ __launch_bounds__(256) void attn_merge_kernel(u16* __restrict__ part0,
                                                         const u16* __restrict__ part1,
                                                         const float2* __restrict__ msum,
                                                         const int* __restrict__ pMr,
                                                         int Mc) {
  const int t = threadIdx.x;
  const int r = blockIdx.x * 2 + (t >> 7);
  if (r >= *pMr) return;
  const int tt = t & 127;
  const int d0 = tt * 4;
  const int h = d0 >> 6;
  float2 s0 = msum[(size_t)h * Mc + r];
  float2 s1 = msum[((size_t)NH + h) * Mc + r];
  float newm = fmaxf(s0.x, s1.x);          // s0.x finite (side 0 has >=1 key)
  float cs0 = __expf(s0.x - newm);
  float cs1 = __expf(s1.x - newm);         // empty side 1: exp(-inf)=0
  float inv = 1.f / (s0.y * cs0 + s1.y * cs1);
  u16* p0 = part0 + (size_t)r * ND + d0;
  const u16* p1 = part1 + (size_t)r * ND + d0;
  u16x4 a = *(u16x4*)p0;
  u16x4 b = *(const u16x4*)p1;
  u16x4 o;
#pragma unroll
  for (int e = 0; e < 4; ++e)
    o[e] = f2b((b2f(a[e]) * cs0 + b2f(b[e]) * cs1) * inv);
  *(u16x4*)p0 = o;
}

// ---------------------------------------------------------------------------
// x = LN(x) * g + b IN-PLACE; writes bf16 mirror xb. VARLEN early-exit.
// ---------------------------------------------------------------------------
__global__ __launch_bounds__(128) void add_ln_kernel(float* __restrict__ x,
                                                     u16* __restrict__ xb,
                                                     const float* __restrict__ g,
                                                     const float* __restrict__ bb,
                                                     const int* __restrict__ pMr) {
  const int row = blockIdx.x;
  if (row >= *pMr) return;
  const int t = threadIdx.x;
  const size_t base = (size_t)row * ND + t * 4;
  float4 v = *(const float4*)(x + base);
  float s = (v.x + v.y) + (v.z + v.w);
  float q = (v.x * v.x + v.y * v.y) + (v.z * v.z + v.w * v.w);
#pragma unroll
  for (int off = 32; off; off >>= 1) {
    s += __shfl_down(s, off);
    q += __shfl_down(q, off);
  }
  __shared__ float sb[4];
  const int wid = t >> 6;
  if ((t & 63) == 0) { sb[wid * 2] = s; sb[wid * 2 + 1] = q; }
  __syncthreads();
  float ts = sb[0] + sb[2];
  float tq = sb[1] + sb[3];
  float mean = ts * (1.f / (float)ND);
  float var = tq * (1.f / (float)ND) - mean * mean;
  float rstd = rsqrtf(var + 1e-5f);
  float4 gg = *(const float4*)(g + t * 4);
  float4 bv = *(const float4*)(bb + t * 4);
  float o0 = (v.x - mean) * rstd * gg.x + bv.x;
  float o1 = (v.y - mean) * rstd * gg.y + bv.y;
  float o2 = (v.z - mean) * rstd * gg.z + bv.z;
  float o3 = (v.w - mean) * rstd * gg.w + bv.w;
  *(float4*)(x + base) = (float4){o0, o1, o2, o3};
  u16x4 ob = {f2b(o0), f2b(o1), f2b(o2), f2b(o3)};
  *(u16x4*)(xb + base) = ob;
}

// ---------------------------------------------------------------------------
// w2sum[d] = sum_o attn_w[o, D + d]   (s_q and attn_b cancel in the softmax)
// ---------------------------------------------------------------------------
__global__ __launch_bounds__(64) void w2sum_kernel(const float* __restrict__ attn_w,
                                                   float* __restrict__ w2sum) {
  int d = blockIdx.x * 64 + threadIdx.x;
  float s = 0.f;
  for (int o = 0; o < ND; ++o) s += attn_w[(size_t)o * 1024 + 512 + d];
  w2sum[d] = s;
}

// ---------------------------------------------------------------------------
// VARLEN pooling head, race-free (round-8 proven).
// ---------------------------------------------------------------------------
__global__ __launch_bounds__(256) void pool_kernel(const float* __restrict__ x,
                                                   const int* __restrict__ offs,
                                                   int BC,
                                                   const float* __restrict__ w2sum,
                                                   float* __restrict__ out) {
  const int b = blockIdx.x;
  const int c = b / BC;
  const int ob = offs[b] - offs[c * BC];
  const int len = offs[b + 1] - offs[b];  // >= 1
  const float* xr0 = x + ((size_t)c * BC * NS + ob) * ND;
  const int t = threadIdx.x;
  __shared__ float wsm[ND];
  __shared__ float sv[NS + 12];
  __shared__ float pv[256];
  __shared__ float red[8];
  wsm[t] = w2sum[t];
  wsm[t + 256] = w2sum[t + 256];
  __syncthreads();
  const int wv = t >> 6, ln = t & 63;
  for (int s = wv; s < len; s += 4) {
    const float* xr = xr0 + (size_t)s * ND;
    float acc = 0.f;
#pragma unroll
    for (int j = 0; j < 8; ++j) acc += xr[ln + j * 64] * wsm[ln + j * 64];
#pragma unroll
    for (int off = 32; off; off >>= 1) acc += __shfl_xor(acc, off);
    if (ln == 0) sv[s] = acc;
  }
  __syncthreads();
  float v = (t < len) ? sv[t] : -INFINITY;
  float m_ = v;
#pragma unroll
  for (int off = 32; off; off >>= 1) m_ = fmaxf(m_, __shfl_xor(m_, off));
  if (ln == 0) red[wv] = m_;
  __syncthreads();
  const float mx = fmaxf(fmaxf(red[0], red[1]), fmaxf(red[2], red[3]));
  float e = (t < len) ? __expf(v - mx) : 0.f;
  pv[t] = e;
  float s_ = e;
#pragma unroll
  for (int off = 32; off; off >>= 1) s_ += __shfl_xor(s_, off);
  if (ln == 0) red[4 + wv] = s_;
  __syncthreads();
  const float inv = 1.f / ((red[4] + red[5]) + (red[6] + red[7]));
  float a0 = 0.f, a1 = 0.f;
  for (int s = 0; s < len; ++s) {
    float p = pv[s];
    const float* xr = xr0 + (size_t)s * ND;
    a0 += p * xr[t];
    a1 += p * xr[t + 256];
  }
  out[(size_t)b * ND + t] = a0 * inv;
  out[(size_t)b * ND + t + 256] = a1 * inv;
}

// ---------------------------------------------------------------------------
extern "C" void kernel_launch(void* const* d_in, const int* in_sizes, int n_in,
                              void* d_out, int out_size, void* d_ws, size_t ws_size,
                              hipStream_t stream) {
  const int* mask = (const int*)d_in[0];
  const float* emb = (const float*)d_in[1];
  const float* in_proj_w = (const float*)d_in[2];
  const float* in_proj_b = (const float*)d_in[3];
  const float* out_proj_w = (const float*)d_in[4];
  const float* out_proj_b = (const float*)d_in[5];
  const float* lin1_w = (const float*)d_in[6];
  const float* lin1_b = (const float*)d_in[7];
  const float* lin2_w = (const float*)d_in[8];
  const float* lin2_b = (const float*)d_in[9];
  const float* ln1_w = (const float*)d_in[10];
  const float* ln1_b = (const float*)d_in[11];
  const float* ln2_w = (const float*)d_in[12];
  const float* ln2_b = (const float*)d_in[13];
  const float* attn_w = (const float*)d_in[14];
  // d_in[15] = attn_b: constant over softmax axis -> cancels; unused.

  char* wsb = (char*)d_ws;
  size_t off = 0;
  auto alloc = [&](size_t bytes) -> char* {
    char* p = wsb + off;
    off += (bytes + 255) & ~(size_t)255;
    return p;
  };
  float* x   = (float*)alloc((size_t)NM * ND * 4);   // compacted, chunk-strided
  u16* xb    = (u16*)alloc((size_t)NM * ND * 2);     // compacted bf16 mirror
  u16* wqkv  = (u16*)alloc((size_t)NL * 1536 * 512 * 2);
  u16* wout  = (u16*)alloc((size_t)NL * 512 * 512 * 2);
  u16* w1b   = (u16*)alloc((size_t)NL * 2048 * 512 * 2);
  u16* w2b   = (u16*)alloc((size_t)NL * 512 * 2048 * 2);
  float* w2s = (float*)alloc(ND * 4);
  int* offs  = (int*)alloc((NB + 1) * 4);
  int* meta  = (int*)alloc(16 * 4);   // Mr per chunk (<= 8 chunks)
  int* order = (int*)alloc(NB * 4);   // LPT batch order per chunk
  size_t fixedEnd = off;

  int BC = 32;
  const int cands[4] = {256, 128, 64, 32};
  auto alup = [](size_t b) { return (b + 255) & ~(size_t)255; };
  for (int ci = 0; ci < 4; ++ci) {
    size_t Mc = (size_t)cands[ci] * NS;
    if (fixedEnd + alup(Mc * 2048 * 2) <= ws_size) { BC = cands[ci]; break; }
  }
  const size_t Mc = (size_t)BC * NS;
  const int NC = NB / BC;
  u16* big  = (u16*)alloc(Mc * 2048 * 2);   // qkv (Mc x 1536) / h1 (Mc x 2048)
  u16* attO = big + Mc * 1536;              // attn out / split part0 (Mc x 512)

  // Key-split extras (engage only if workspace fits)
  size_t needP1 = alup(Mc * 512 * 2);
  size_t needMS = alup(2 * NH * Mc * 8);
  bool splitOK = (off + needP1 + needMS <= ws_size);
  u16* part1 = nullptr;
  float2* msum = nullptr;
  if (splitOK) {
    part1 = (u16*)alloc(Mc * 512 * 2);
    msum = (float2*)alloc(2 * NH * Mc * 8);
  }

  cast_kernel<<<NL * 1536 * 512 / 1024, 256, 0, stream>>>(in_proj_w, wqkv);
  cast_kernel<<<NL * 512 * 512 / 1024, 256, 0, stream>>>(out_proj_w, wout);
  cast_kernel<<<NL * 2048 * 512 / 1024, 256, 0, stream>>>(lin1_w, w1b);
  cast_kernel<<<NL * 512 * 2048 / 1024, 256, 0, stream>>>(lin2_w, w2b);
  scan_kernel<<<1, 256, 0, stream>>>(mask, offs, meta, order, BC, NC);
  pe_compact_kernel<<<NM, 128, 0, stream>>>(emb, offs, BC, x, xb);

  for (int i = 0; i < NL; ++i) {
    for (int c = 0; c < NC; ++c) {
      float* xc = x + (size_t)c * Mc * ND;
      u16* xbc = xb + (size_t)c * Mc * ND;
      const int* pMr = meta + c;
      gemm_mfma<128, false, true, false><<<dim3(1536 / 128, Mc / 128), 256, 0, stream>>>(
          xbc, wqkv + (size_t)i * 1536 * 512, in_proj_b + i * 1536, nullptr, nullptr, big, pMr, 1536, 512);
      if (splitOK) {
        attn_split_kernel<<<dim3(BC * NH, 2), 128, 0, stream>>>(
            big, offs, order, c * BC, (int)Mc, attO, part1, msum);
        attn_merge_kernel<<<Mc / 2, 256, 0, stream>>>(attO, part1, msum, pMr, (int)Mc);
      } else {
        attn_kernel<<<BC * NH, 128, 0, stream>>>(big, offs, order, c * BC, attO);
      }
      gemm_mfma<64, false, false, true><<<dim3(512 / 128, Mc / 64), 256, 0, stream>>>(
          attO, wout + (size_t)i * 512 * 512, out_proj_b + i * 512, xc, xc, nullptr, pMr, 512, 512);
      add_ln_kernel<<<Mc, 128, 0, stream>>>(xc, xbc, ln1_w + i * 512, ln1_b + i * 512, pMr);
      gemm_mfma<128, true, true, false><<<dim3(2048 / 128, Mc / 128), 256, 0, stream>>>(
          xbc, w1b + (size_t)i * 2048 * 512, lin1_b + i * 2048, nullptr, nullptr, big, pMr, 2048, 512);
      gemm_mfma<64, false, false, true><<<dim3(512 / 128, Mc / 64), 256, 0, stream>>>(
          big, w2b + (size_t)i * 512 * 2048, lin2_b + i * 512, xc, xc, nullptr, pMr, 512, 2048);
      add_ln_kernel<<<Mc, 128, 0, stream>>>(xc, xbc, ln2_w + i * 512, ln2_b + i * 512, pMr);
    }
  }

  w2sum_kernel<<<ND / 64, 64, 0, stream>>>(attn_w, w2s);
  pool_kernel<<<NB, 256, 0, stream>>>(x, offs, BC, w2s, (float*)d_out);
}